// Round 9
// baseline (126.329 us; speedup 1.0000x reference)
//
#include <hip/hip_runtime.h>

#define BB 8
#define NN 128
#define CC 32

struct ParamsA {
  const float* __restrict__ atom0; const float* __restrict__ atom1; const float* __restrict__ atom2;
  const float* __restrict__ edge0; const float* __restrict__ edge1; const float* __restrict__ edge2;
  const void*  mask;
  const float* __restrict__ cg[14];
  float* __restrict__ ws;   // [node][48*32] aggregated cat columns
};

struct ParamsB {
  const float* __restrict__ atom0; const float* __restrict__ atom1; const float* __restrict__ atom2;
  const float* __restrict__ cg[14];
  const float* __restrict__ w0; const float* __restrict__ w1; const float* __restrict__ w2;
  const float* __restrict__ ws;
  float* __restrict__ out;
};

// ================= Kernel 1: masked neighbor aggregation =================
// Block = (b,i), 512 threads = 32 c x 16 slots (sx = x-half, jp = j-slot).
// No compaction: all 128 j processed, mask folded as float multiplier.
// Groups of 8 j staged into LDS (float4, affine addresses), register 2-deep
// prefetch: loads for group g issued a full iteration before their ds_write.
// Staged row layout per j (576 floats): [a0:0][a1:32][a2:128][e0:288][e1:320][e2:416]
__global__ __launch_bounds__(512, 2) void lgn_agg(ParamsA p) {
  const int tid = threadIdx.x;
  const int c   = tid & 31;
  const int s   = tid >> 5;      // 0..15
  const int sx  = s >> 3;        // wave-uniform x-half
  const int jp  = s & 7;         // j-slot
  const int blk = blockIdx.x;
  const int b   = blk & 7;       // XCD-friendly
  const int i   = blk >> 3;

  __shared__ float arena[9216];  // stage dbuf 2x4608; reused: reduce slabs 2x2880; O flat 2592
  __shared__ float sm_cg[540];
  __shared__ float sm_wts[128];
  __shared__ int   sm_mode;

  // ---- probe mask dtype ----
  if (tid == 0) sm_mode = 0;
  __syncthreads();
  if (tid < 64) {
    unsigned v = ((const unsigned*)p.mask)[tid];
    if (v == 0x3F800000u) atomicOr(&sm_mode, 2);   // float32
    else if (v > 1u)      atomicOr(&sm_mode, 1);   // packed bytes
  }
  // ---- stage cg ----
  {
    constexpr int CGSZ[14] = {1,9,25, 9,9,27,45,45, 25,45,75,25,75,125};
    constexpr int CGOF[14] = {0,1,10, 35,44,53,80,125, 170,195,240,315,340,415};
    #pragma unroll
    for (int t = 0; t < 14; ++t)
      for (int idx = tid; idx < CGSZ[t]; idx += 512)
        sm_cg[CGOF[t] + idx] = p.cg[t][idx];
  }
  __syncthreads();
  const int mode = (sm_mode & 2) ? 2 : sm_mode;

  // ---- stage mask row as float weights ----
  if (tid < 128) {
    const int midx = (b * NN + i) * NN + tid;
    bool mv;
    if (mode == 0)      mv = ((const int*)p.mask)[midx] != 0;
    else if (mode == 2) mv = ((const float*)p.mask)[midx] != 0.f;
    else                mv = ((const unsigned char*)p.mask)[midx] != 0;
    sm_wts[tid] = mv ? 1.f : 0.f;
  }

  // ---- staging descriptors (affine: addr = srcB + j*jmul) ----
  const float* srcB[3]; int jmul[3], dstO[3], jgk[3];
  {
    const long ab = (long)b * NN;
    const long eb = (long)(b * NN + i) * NN;
    #pragma unroll
    for (int k = 0; k < 3; ++k) {
      const int f  = tid + k * 512;
      const int jg = f / 144;
      const int r  = f - jg * 144;
      jgk[k] = jg;
      if (r < 8)        { srcB[k] = p.atom0 + ab *  32 + r * 4;              jmul[k] =  32; dstO[k] = jg * 576 +   0 + r * 4; }
      else if (r < 32)  { int q = r - 8;   srcB[k] = p.atom1 + ab *  96 + q * 4; jmul[k] =  96; dstO[k] = jg * 576 +  32 + q * 4; }
      else if (r < 72)  { int q = r - 32;  srcB[k] = p.atom2 + ab * 160 + q * 4; jmul[k] = 160; dstO[k] = jg * 576 + 128 + q * 4; }
      else if (r < 80)  { int q = r - 72;  srcB[k] = p.edge0 + eb *  32 + q * 4; jmul[k] =  32; dstO[k] = jg * 576 + 288 + q * 4; }
      else if (r < 104) { int q = r - 80;  srcB[k] = p.edge1 + eb *  96 + q * 4; jmul[k] =  96; dstO[k] = jg * 576 + 320 + q * 4; }
      else              { int q = r - 104; srcB[k] = p.edge2 + eb * 160 + q * 4; jmul[k] = 160; dstO[k] = jg * 576 + 416 + q * 4; }
    }
  }

  float acc[5][9];
  #pragma unroll
  for (int k = 0; k < 5; ++k)
    #pragma unroll
    for (int y = 0; y < 9; ++y) acc[k][y] = 0.f;

#define LOADG(V0, V1, V2, G) do {                                           \
    V0 = *(const float4*)(srcB[0] + (long)((G) * 8 + jgk[0]) * jmul[0]);    \
    V1 = *(const float4*)(srcB[1] + (long)((G) * 8 + jgk[1]) * jmul[1]);    \
    if (tid < 128)                                                          \
      V2 = *(const float4*)(srcB[2] + (long)((G) * 8 + jgk[2]) * jmul[2]);  \
  } while (0)

#define WRITEG(V0, V1, V2, G) do {                                          \
    float* bp_ = arena + ((G) & 1) * 4608;                                  \
    *(float4*)(bp_ + dstO[0]) = V0;                                         \
    *(float4*)(bp_ + dstO[1]) = V1;                                         \
    if (tid < 128) *(float4*)(bp_ + dstO[2]) = V2;                          \
  } while (0)

#define CONSUME(T) do {                                                     \
    const float* bp = arena + ((T) & 1) * 4608 + jp * 576;                  \
    const float wt = sm_wts[(T) * 8 + jp];                                  \
    float e[9];                                                             \
    e[0] = bp[288 + c];                                                     \
    _Pragma("unroll")                                                       \
    for (int y = 0; y < 3; ++y) e[1 + y] = bp[320 + c * 3 + y];             \
    _Pragma("unroll")                                                       \
    for (int y = 0; y < 5; ++y) e[4 + y] = bp[416 + c * 5 + y];             \
    if (sx == 0) {                                                          \
      float a[4];                                                           \
      a[0] = bp[c];                                                         \
      _Pragma("unroll")                                                     \
      for (int y = 0; y < 3; ++y) a[1 + y] = bp[32 + c * 3 + y];            \
      _Pragma("unroll")                                                     \
      for (int k = 0; k < 4; ++k) {                                         \
        const float av = a[k] * wt;                                         \
        _Pragma("unroll")                                                   \
        for (int y = 0; y < 9; ++y) acc[k][y] += av * e[y];                 \
      }                                                                     \
    } else {                                                                \
      float a[5];                                                           \
      _Pragma("unroll")                                                     \
      for (int y = 0; y < 5; ++y) a[y] = bp[128 + c * 5 + y];               \
      _Pragma("unroll")                                                     \
      for (int k = 0; k < 5; ++k) {                                         \
        const float av = a[k] * wt;                                         \
        _Pragma("unroll")                                                   \
        for (int y = 0; y < 9; ++y) acc[k][y] += av * e[y];                 \
      }                                                                     \
    }                                                                       \
  } while (0)

  {
    float4 c0, c1, c2, n0, n1, n2;
    // prologue: group 0 staged, group 1 loads in flight
    LOADG(c0, c1, c2, 0);
    WRITEG(c0, c1, c2, 0);
    LOADG(c0, c1, c2, 1);
    __syncthreads();
    for (int T = 0; T < 16; T += 2) {
      // iter T (even): prefetch T+2, consume T, write T+1 (loaded 1 iter ago)
      if (T + 2 < 16) LOADG(n0, n1, n2, T + 2);
      CONSUME(T);
      WRITEG(c0, c1, c2, T + 1);
      __syncthreads();
      // iter T+1 (odd): prefetch T+3, consume T+1, write T+2
      if (T + 3 < 16) LOADG(c0, c1, c2, T + 3);
      CONSUME(T + 1);
      if (T + 2 < 16) WRITEG(n0, n1, n2, T + 2);
      __syncthreads();
    }
  }
#undef LOADG
#undef WRITEG
#undef CONSUME

  // ---- tree reduce 8 jp-slots (2 slabs of 45x64 in arena) ----
  const int sc = sx * 32 + c;
  if (jp >= 6) {
    float* sp = &arena[(jp - 6) * 2880 + sc];
    #pragma unroll
    for (int k = 0; k < 5; ++k)
      #pragma unroll
      for (int y = 0; y < 9; ++y) sp[(k * 9 + y) * 64] = acc[k][y];
  }
  __syncthreads();
  if (jp == 4 || jp == 5) {
    const float* sp = &arena[(jp - 4) * 2880 + sc];
    #pragma unroll
    for (int k = 0; k < 5; ++k)
      #pragma unroll
      for (int y = 0; y < 9; ++y) acc[k][y] += sp[(k * 9 + y) * 64];
  }
  __syncthreads();
  if (jp == 4 || jp == 5) {
    float* sp = &arena[(jp - 4) * 2880 + sc];
    #pragma unroll
    for (int k = 0; k < 5; ++k)
      #pragma unroll
      for (int y = 0; y < 9; ++y) sp[(k * 9 + y) * 64] = acc[k][y];
  }
  __syncthreads();
  if (jp <= 1) {
    const float* sp = &arena[jp * 2880 + sc];
    #pragma unroll
    for (int k = 0; k < 5; ++k)
      #pragma unroll
      for (int y = 0; y < 9; ++y) acc[k][y] += sp[(k * 9 + y) * 64];
  }
  __syncthreads();
  if (jp == 2 || jp == 3) {
    float* sp = &arena[(jp - 2) * 2880 + sc];
    #pragma unroll
    for (int k = 0; k < 5; ++k)
      #pragma unroll
      for (int y = 0; y < 9; ++y) sp[(k * 9 + y) * 64] = acc[k][y];
  }
  __syncthreads();
  if (jp <= 1) {
    const float* sp = &arena[jp * 2880 + sc];
    #pragma unroll
    for (int k = 0; k < 5; ++k)
      #pragma unroll
      for (int y = 0; y < 9; ++y) acc[k][y] += sp[(k * 9 + y) * 64];
  }
  #pragma unroll
  for (int k = 0; k < 5; ++k)
    #pragma unroll
    for (int y = 0; y < 9; ++y) acc[k][y] += __shfl_down(acc[k][y], 32);
  __syncthreads();   // slab reads done before O overwrites

  // ---- write final O flat [c][x*9+y] at arena[0..2591] ----
  if (s == 0) {
    #pragma unroll
    for (int k = 0; k < 4; ++k)
      #pragma unroll
      for (int y = 0; y < 9; ++y) arena[c * 81 + k * 9 + y] = acc[k][y];
  } else if (s == 8) {
    #pragma unroll
    for (int k = 0; k < 5; ++k)
      #pragma unroll
      for (int y = 0; y < 9; ++y) arena[c * 81 + (4 + k) * 9 + y] = acc[k][y];
  }
  __syncthreads();

  // ---- contract O with CG -> 48 aggregated floats per channel -> ws ----
  {
    constexpr int aggD[14]  = {1,1,1, 3,3,3,3,3, 5,5,5,5,5,5};
    constexpr int aggL1[14] = {0,1,2, 0,1,1,1,2, 0,1,1,2,2,2};
    constexpr int aggL2[14] = {0,1,2, 1,0,1,2,1, 2,1,2,0,1,2};
    constexpr int aggCg[14] = {0,1,10, 35,44,53,80,125, 170,195,240,315,340,415};
    constexpr int aggF[14]  = {0,1,2, 3,6,9,12,15, 18,23,28,33,38,43};
    constexpr int DD[3]     = {1,3,5};
    constexpr int aOff[3]   = {0,1,4};
    const long wsbase = (long)(b * NN + i) * 1536;
    if (s < 14) {
      const int col = s;
      const int d = aggD[col], f0 = aggF[col];
      const int l1 = aggL1[col], l2 = aggL2[col];
      const int d1 = DD[l1], d2 = DD[l2];
      const int x0 = aOff[l1], y0 = aOff[l2];
      const float* cgp = &sm_cg[aggCg[col]];
      const float* Ofl = &arena[c * 81];
      for (int z = 0; z < d; ++z) {
        float sum = 0.f;
        for (int xi = 0; xi < d1; ++xi)
          for (int yi = 0; yi < d2; ++yi)
            sum += Ofl[(x0 + xi) * 9 + y0 + yi] * cgp[(xi * d2 + yi) * d + z];
        p.ws[wsbase + (f0 + z) * 32 + c] = sum;
      }
    }
  }
}

// ================= Kernel 2: cat assembly + channel mix =================
// Block = node, 256 threads = 32 c x 8 g-slots. High VGPR budget so the
// 124 w-loads per thread are register-hoisted (static indices) and pipeline.
__global__ __launch_bounds__(256, 1) void lgn_mix(ParamsB p) {
  const int tid = threadIdx.x;
  const int c   = tid & 31;
  const int g   = tid >> 5;    // 0..7
  const int blk = blockIdx.x;
  const int b   = blk & 7;
  const int i   = blk >> 3;
  const int node = b * NN + i;

  __shared__ float sm_cat[3360];
  __shared__ float sm_cg[540];
  __shared__ float sm_ai[288];
  __shared__ float sm_mix[1152];   // 4 slabs x 288

  // ---- stage cg + node atoms ----
  {
    constexpr int CGSZ[14] = {1,9,25, 9,9,27,45,45, 25,45,75,25,75,125};
    constexpr int CGOF[14] = {0,1,10, 35,44,53,80,125, 170,195,240,315,340,415};
    #pragma unroll
    for (int t = 0; t < 14; ++t)
      for (int idx = tid; idx < CGSZ[t]; idx += 256)
        sm_cg[CGOF[t] + idx] = p.cg[t][idx];
    const int nodeBase = node * CC;
    for (int s2 = tid; s2 < 288; s2 += 256) {
      int cc = s2 / 9, comp = s2 - cc * 9;
      float v;
      if (comp == 0)      v = p.atom0[nodeBase + cc];
      else if (comp < 4)  v = p.atom1[(nodeBase + cc) * 3 + comp - 1];
      else                v = p.atom2[(nodeBase + cc) * 5 + comp - 4];
      sm_ai[s2] = v;
    }
  }
  __syncthreads();

  const float* wsp = p.ws + (long)node * 1536;

  // ---- build cat (aggregate copy | identity | power) ----
  {
    constexpr int colL[31]   = {0,0,0,0,0,0,0, 1,1,1,1,1,1,1,1,1,1,1, 2,2,2,2,2,2,2,2,2,2,2,2,2};
    constexpr int colKind[31]= {0,0,0,1,2,2,2, 0,0,0,0,0,1,2,2,2,2,2, 0,0,0,0,0,0,1,2,2,2,2,2,2};
    constexpr int colL1[31]  = {0,1,2,0,0,1,2, 0,1,1,1,2,0,0,1,1,1,2, 0,1,1,2,2,2,0,0,1,1,2,2,2};
    constexpr int colL2[31]  = {0,1,2,0,0,1,2, 1,0,1,2,1,0,1,0,1,2,1, 2,1,2,0,1,2,0,2,1,2,0,1,2};
    constexpr int colCg[31]  = {0,1,10,0,0,1,10, 35,44,53,80,125,0,35,44,53,80,125,
                                170,195,240,315,340,415,0,170,195,240,315,340,415};
    constexpr int colP[31]   = {0,1,2,3,4,5,6, 0,1,2,3,4,5,6,7,8,9,10, 0,1,2,3,4,5,6,7,8,9,10,11,12};
    constexpr int colF[31]   = {0,1,2,-1,-1,-1,-1, 3,6,9,12,15,-1,-1,-1,-1,-1,-1,
                                18,23,28,33,38,43,-1,-1,-1,-1,-1,-1,-1};
    constexpr int DD[3]      = {1,3,5};
    constexpr int catBase[3] = {0,224,1280};
    constexpr int aOff[3]    = {0,1,4};

    for (int col = g; col < 31; col += 8) {
      const int l = colL[col];
      const int d = DD[l];
      const int kind = colKind[col];
      float* catp = &sm_cat[catBase[l] + (colP[col] * CC + c) * d];
      if (kind == 0) {            // aggregate: staged from ws
        const int f0 = colF[col];
        for (int z = 0; z < d; ++z) catp[z] = wsp[(f0 + z) * 32 + c];
      } else if (kind == 1) {     // identity
        for (int z = 0; z < d; ++z) catp[z] = sm_ai[c * 9 + aOff[l] + z];
      } else {                    // power
        const int l1 = colL1[col], l2 = colL2[col];
        const int d1 = DD[l1], d2 = DD[l2];
        const float* cgp = &sm_cg[colCg[col]];
        const float* a1p = &sm_ai[c * 9 + aOff[l1]];
        const float* a2p = &sm_ai[c * 9 + aOff[l2]];
        for (int z = 0; z < d; ++z) {
          float sum = 0.f;
          for (int xi = 0; xi < d1; ++xi)
            for (int yi = 0; yi < d2; ++yi)
              sum += a1p[xi] * a2p[yi] * cgp[(xi * d2 + yi) * d + z];
          catp[z] = sum;
        }
      }
    }
  }

  // ---- hoist all w values for this (g,c) into registers (static idx) ----
  float w0r[28], w1r[44], w2r[52];
  #pragma unroll
  for (int u = 0; u < 28; ++u) w0r[u] = p.w0[(g + u * 8) * CC + c];
  #pragma unroll
  for (int u = 0; u < 44; ++u) w1r[u] = p.w1[(g + u * 8) * CC + c];
  #pragma unroll
  for (int u = 0; u < 52; ++u) w2r[u] = p.w2[(g + u * 8) * CC + c];
  __syncthreads();   // cat complete

  // ---- channel mix (8-way k-split) ----
  {
    float accm[9];
    #pragma unroll
    for (int q = 0; q < 9; ++q) accm[q] = 0.f;
    #pragma unroll
    for (int u = 0; u < 28; ++u)
      accm[0] += sm_cat[g + u * 8] * w0r[u];
    #pragma unroll
    for (int u = 0; u < 44; ++u) {
      const int k = g + u * 8;
      const float wv = w1r[u];
      accm[1] += sm_cat[224 + k * 3 + 0] * wv;
      accm[2] += sm_cat[224 + k * 3 + 1] * wv;
      accm[3] += sm_cat[224 + k * 3 + 2] * wv;
    }
    #pragma unroll
    for (int u = 0; u < 52; ++u) {
      const int k = g + u * 8;
      const float wv = w2r[u];
      #pragma unroll
      for (int z = 0; z < 5; ++z)
        accm[4 + z] += sm_cat[1280 + k * 5 + z] * wv;
    }
    #pragma unroll
    for (int q = 0; q < 9; ++q) accm[q] += __shfl_down(accm[q], 32);
    if ((g & 1) == 0) {
      #pragma unroll
      for (int q = 0; q < 9; ++q)
        sm_mix[(g >> 1) * 288 + c * 9 + q] = accm[q];
    }
  }
  __syncthreads();

  // ---- final partial-sum + store ----
  for (int s2 = tid; s2 < 288; s2 += 256) {
    float v = sm_mix[s2] + sm_mix[288 + s2] + sm_mix[576 + s2] + sm_mix[864 + s2];
    const int co = s2 / 9, zz = s2 - co * 9;
    const int nb = node * CC;
    int oidx;
    if (zz == 0)     oidx = nb + co;                           // l=0
    else if (zz < 4) oidx = 32768  + (nb + co) * 3 + (zz - 1); // l=1
    else             oidx = 131072 + (nb + co) * 5 + (zz - 4); // l=2
    p.out[oidx] = v;
  }
}

extern "C" void kernel_launch(void* const* d_in, const int* in_sizes, int n_in,
                              void* d_out, int out_size, void* d_ws, size_t ws_size,
                              hipStream_t stream) {
  const float *atom0, *atom1, *atom2, *edge0, *edge1, *edge2;
  const bool interleaved = (in_sizes[1] == BB * NN * NN * CC);
  if (interleaved) {
    atom0 = (const float*)d_in[0]; edge0 = (const float*)d_in[1];
    atom1 = (const float*)d_in[2]; edge1 = (const float*)d_in[3];
    atom2 = (const float*)d_in[4]; edge2 = (const float*)d_in[5];
  } else {
    atom0 = (const float*)d_in[0]; atom1 = (const float*)d_in[1]; atom2 = (const float*)d_in[2];
    edge0 = (const float*)d_in[3]; edge1 = (const float*)d_in[4]; edge2 = (const float*)d_in[5];
  }

  ParamsA pa;
  pa.atom0 = atom0; pa.atom1 = atom1; pa.atom2 = atom2;
  pa.edge0 = edge0; pa.edge1 = edge1; pa.edge2 = edge2;
  pa.mask  = d_in[6];
  for (int t = 0; t < 14; ++t) pa.cg[t] = (const float*)d_in[7 + t];
  pa.ws = (float*)d_ws;

  ParamsB pb;
  pb.atom0 = atom0; pb.atom1 = atom1; pb.atom2 = atom2;
  for (int t = 0; t < 14; ++t) pb.cg[t] = (const float*)d_in[7 + t];
  pb.w0 = (const float*)d_in[21];
  pb.w1 = (const float*)d_in[22];
  pb.w2 = (const float*)d_in[23];
  pb.ws = (const float*)d_ws;
  pb.out = (float*)d_out;

  lgn_agg<<<dim3(BB * NN), dim3(512), 0, stream>>>(pa);
  lgn_mix<<<dim3(BB * NN), dim3(256), 0, stream>>>(pb);
}

// Round 10
// 99.491 us; speedup vs baseline: 1.2698x; 1.2698x over previous
//
#include <hip/hip_runtime.h>

#define BB 8
#define NN 128
#define CC 32

struct Params {
  const float* __restrict__ atom0; const float* __restrict__ atom1; const float* __restrict__ atom2;
  const float* __restrict__ edge0; const float* __restrict__ edge1; const float* __restrict__ edge2;
  const void*  mask;
  const float* __restrict__ cg[14];
  const float* __restrict__ w0; const float* __restrict__ w1; const float* __restrict__ w2;
  float* __restrict__ out;
};

// Fused kernel: block = (b,i), 512 threads = 32 c x 16 slots.
// slot s: sx = s>>3 (x-half: waves 0-3 rows 0..3, waves 4-7 rows 4..8), jp = s&7.
// Main loop: BARRIER-FREE. Per-thread direct global loads (registers only),
// 2-deep rotation so group t+1 loads are in flight during group t FMAs.
__global__ __launch_bounds__(512, 2) void lgn_fused(Params p) {
  const int tid = threadIdx.x;
  const int c   = tid & 31;
  const int s   = tid >> 5;      // 0..15
  const int sx  = s >> 3;        // wave-uniform x-half
  const int jp  = s & 7;         // j-slot
  const int blk = blockIdx.x;
  const int b   = blk & 7;       // XCD-friendly
  const int i   = blk >> 3;

  // arena: reduce slabs 2x2880 | then O 0..2591, cat 2592..5951, mix 5952..8255
  __shared__ float arena[8256];
  __shared__ float sm_cg[540];
  __shared__ float sm_ai[288];
  __shared__ int   sm_list[128];
  __shared__ int   sm_nact, sm_mode;

  // ---- probe mask dtype ----
  if (tid == 0) sm_mode = 0;
  __syncthreads();
  if (tid < 64) {
    unsigned v = ((const unsigned*)p.mask)[tid];
    if (v == 0x3F800000u) atomicOr(&sm_mode, 2);   // float32
    else if (v > 1u)      atomicOr(&sm_mode, 1);   // packed bytes
  }
  // ---- stage cg + node-i atoms ----
  {
    constexpr int CGSZ[14] = {1,9,25, 9,9,27,45,45, 25,45,75,25,75,125};
    constexpr int CGOF[14] = {0,1,10, 35,44,53,80,125, 170,195,240,315,340,415};
    #pragma unroll
    for (int t = 0; t < 14; ++t)
      for (int idx = tid; idx < CGSZ[t]; idx += 512)
        sm_cg[CGOF[t] + idx] = p.cg[t][idx];
    const int nodeBase = (b * NN + i) * CC;
    for (int s2 = tid; s2 < 288; s2 += 512) {
      int cc = s2 / 9, comp = s2 - cc * 9;
      float v;
      if (comp == 0)      v = p.atom0[nodeBase + cc];
      else if (comp < 4)  v = p.atom1[(nodeBase + cc) * 3 + comp - 1];
      else                v = p.atom2[(nodeBase + cc) * 5 + comp - 4];
      sm_ai[s2] = v;
    }
  }
  __syncthreads();
  const int mode = (sm_mode & 2) ? 2 : sm_mode;

  // ---- ballot compaction of 128-j mask row (wave 0) ----
  if (tid < 64) {
    const int row = (b * NN + i) * NN;
    bool mv0, mv1;
    if (mode == 0) {
      mv0 = ((const int*)p.mask)[row + tid] != 0;
      mv1 = ((const int*)p.mask)[row + tid + 64] != 0;
    } else if (mode == 2) {
      mv0 = ((const float*)p.mask)[row + tid] != 0.f;
      mv1 = ((const float*)p.mask)[row + tid + 64] != 0.f;
    } else {
      mv0 = ((const unsigned char*)p.mask)[row + tid] != 0;
      mv1 = ((const unsigned char*)p.mask)[row + tid + 64] != 0;
    }
    unsigned long long b0 = __ballot(mv0);
    unsigned long long b1 = __ballot(mv1);
    int n0 = (int)__popcll(b0);
    unsigned long long lt = (1ull << tid) - 1ull;
    if (mv0) sm_list[__popcll(b0 & lt)] = tid;
    if (mv1) sm_list[n0 + __popcll(b1 & lt)] = tid + 64;
    if (tid == 0) sm_nact = n0 + (int)__popcll(b1);
  }
  __syncthreads();
  const int nact = sm_nact;
  const int nt   = (nact + 7) >> 3;
  // pad list to 128 entries with a valid j
  if (tid < 64) {
    const int j0 = (nact > 0) ? sm_list[0] : 0;
    if (tid      >= nact) sm_list[tid]      = j0;
    if (tid + 64 >= nact) sm_list[tid + 64] = j0;
  }
  __syncthreads();

  // ---- main loop: per-thread direct loads, 2-deep rotation, no barriers ----
  float acc[5][9];
  #pragma unroll
  for (int k = 0; k < 5; ++k)
    #pragma unroll
    for (int y = 0; y < 9; ++y) acc[k][y] = 0.f;

  const float* e0b = p.edge0 + ((long)(b * NN + i) * NN) * CC + c;
  const float* e1b = p.edge1 + (((long)(b * NN + i) * NN) * CC + c) * 3;
  const float* e2b = p.edge2 + (((long)(b * NN + i) * NN) * CC + c) * 5;
  const float* a0b = p.atom0 +  (long)b * NN * CC + c;
  const float* a1b = p.atom1 + ((long)b * NN * CC + c) * 3;
  const float* a2b = p.atom2 + ((long)b * NN * CC + c) * 5;

#define LOADT(E, A, W, T) do {                                              \
    const int idx_ = (T) * 8 + jp;                                          \
    const int j_   = sm_list[idx_ & 127];                                   \
    W = (idx_ < nact) ? 1.f : 0.f;                                          \
    E[0] = e0b[j_ * 32];                                                    \
    { const float* ep_ = e1b + j_ * 96;                                     \
      E[1] = ep_[0]; E[2] = ep_[1]; E[3] = ep_[2]; }                        \
    { const float* ep_ = e2b + j_ * 160;                                    \
      E[4] = ep_[0]; E[5] = ep_[1]; E[6] = ep_[2];                          \
      E[7] = ep_[3]; E[8] = ep_[4]; }                                       \
    if (sx == 0) {                                                          \
      A[0] = a0b[j_ * 32];                                                  \
      const float* ap_ = a1b + j_ * 96;                                     \
      A[1] = ap_[0]; A[2] = ap_[1]; A[3] = ap_[2]; A[4] = 0.f;              \
    } else {                                                                \
      const float* ap_ = a2b + j_ * 160;                                    \
      A[0] = ap_[0]; A[1] = ap_[1]; A[2] = ap_[2];                          \
      A[3] = ap_[3]; A[4] = ap_[4];                                         \
    }                                                                       \
  } while (0)

#define FMAT(E, A, W) do {                                                  \
    if (sx == 0) {                                                          \
      _Pragma("unroll")                                                     \
      for (int k = 0; k < 4; ++k) {                                         \
        const float av_ = A[k] * W;                                         \
        _Pragma("unroll")                                                   \
        for (int y = 0; y < 9; ++y) acc[k][y] += av_ * E[y];                \
      }                                                                     \
    } else {                                                                \
      _Pragma("unroll")                                                     \
      for (int k = 0; k < 5; ++k) {                                         \
        const float av_ = A[k] * W;                                         \
        _Pragma("unroll")                                                   \
        for (int y = 0; y < 9; ++y) acc[k][y] += av_ * E[y];                \
      }                                                                     \
    }                                                                       \
  } while (0)

  if (nact > 0) {
    float eA[9], aA[5], wA;
    float eB[9], aB[5], wB;
    LOADT(eA, aA, wA, 0);
    LOADT(eB, aB, wB, 1);
    const int ntp = (nt + 1) & ~1;   // even-padded trip count
    for (int t = 0; t < ntp; t += 2) {
      FMAT(eA, aA, wA);
      if (t + 2 < ntp) LOADT(eA, aA, wA, t + 2);
      FMAT(eB, aB, wB);
      if (t + 3 < ntp) LOADT(eB, aB, wB, t + 3);
    }
  }
#undef LOADT
#undef FMAT

  __syncthreads();   // all waves done accumulating before slab use

  // ---- tree reduce 8 jp-slots (2 slabs of 45x64 in arena) ----
  const int sc = sx * 32 + c;
  if (jp >= 6) {
    float* sp = &arena[(jp - 6) * 2880 + sc];
    #pragma unroll
    for (int k = 0; k < 5; ++k)
      #pragma unroll
      for (int y = 0; y < 9; ++y) sp[(k * 9 + y) * 64] = acc[k][y];
  }
  __syncthreads();
  if (jp == 4 || jp == 5) {
    const float* sp = &arena[(jp - 4) * 2880 + sc];
    #pragma unroll
    for (int k = 0; k < 5; ++k)
      #pragma unroll
      for (int y = 0; y < 9; ++y) acc[k][y] += sp[(k * 9 + y) * 64];
  }
  __syncthreads();
  if (jp == 4 || jp == 5) {
    float* sp = &arena[(jp - 4) * 2880 + sc];
    #pragma unroll
    for (int k = 0; k < 5; ++k)
      #pragma unroll
      for (int y = 0; y < 9; ++y) sp[(k * 9 + y) * 64] = acc[k][y];
  }
  __syncthreads();
  if (jp <= 1) {
    const float* sp = &arena[jp * 2880 + sc];
    #pragma unroll
    for (int k = 0; k < 5; ++k)
      #pragma unroll
      for (int y = 0; y < 9; ++y) acc[k][y] += sp[(k * 9 + y) * 64];
  }
  __syncthreads();
  if (jp == 2 || jp == 3) {
    float* sp = &arena[(jp - 2) * 2880 + sc];
    #pragma unroll
    for (int k = 0; k < 5; ++k)
      #pragma unroll
      for (int y = 0; y < 9; ++y) sp[(k * 9 + y) * 64] = acc[k][y];
  }
  __syncthreads();
  if (jp <= 1) {
    const float* sp = &arena[jp * 2880 + sc];
    #pragma unroll
    for (int k = 0; k < 5; ++k)
      #pragma unroll
      for (int y = 0; y < 9; ++y) acc[k][y] += sp[(k * 9 + y) * 64];
  }
  #pragma unroll
  for (int k = 0; k < 5; ++k)
    #pragma unroll
    for (int y = 0; y < 9; ++y) acc[k][y] += __shfl_down(acc[k][y], 32);
  __syncthreads();   // slab reads done before O overwrites

  // ---- write final O flat [c][x*9+y] at arena[0..2591] ----
  if (s == 0) {
    #pragma unroll
    for (int k = 0; k < 4; ++k)
      #pragma unroll
      for (int y = 0; y < 9; ++y) arena[c * 81 + k * 9 + y] = acc[k][y];
  } else if (s == 8) {
    #pragma unroll
    for (int k = 0; k < 5; ++k)
      #pragma unroll
      for (int y = 0; y < 9; ++y) arena[c * 81 + (4 + k) * 9 + y] = acc[k][y];
  }
  __syncthreads();

  // ---- build cat (aggregate | identity | power) at arena[2592..] ----
  {
    constexpr int colL[31]   = {0,0,0,0,0,0,0, 1,1,1,1,1,1,1,1,1,1,1, 2,2,2,2,2,2,2,2,2,2,2,2,2};
    constexpr int colKind[31]= {0,0,0,1,2,2,2, 0,0,0,0,0,1,2,2,2,2,2, 0,0,0,0,0,0,1,2,2,2,2,2,2};
    constexpr int colL1[31]  = {0,1,2,0,0,1,2, 0,1,1,1,2,0,0,1,1,1,2, 0,1,1,2,2,2,0,0,1,1,2,2,2};
    constexpr int colL2[31]  = {0,1,2,0,0,1,2, 1,0,1,2,1,0,1,0,1,2,1, 2,1,2,0,1,2,0,2,1,2,0,1,2};
    constexpr int colCg[31]  = {0,1,10,0,0,1,10, 35,44,53,80,125,0,35,44,53,80,125,
                                170,195,240,315,340,415,0,170,195,240,315,340,415};
    constexpr int colP[31]   = {0,1,2,3,4,5,6, 0,1,2,3,4,5,6,7,8,9,10, 0,1,2,3,4,5,6,7,8,9,10,11,12};
    constexpr int DD[3]      = {1,3,5};
    constexpr int catBase[3] = {0,224,1280};
    constexpr int aOff[3]    = {0,1,4};

    for (int col = s; col < 31; col += 16) {
      const int l = colL[col];
      const int d = DD[l];
      const int kind = colKind[col];
      float* catp = &arena[2592 + catBase[l] + (colP[col] * CC + c) * d];
      if (kind == 1) {            // identity
        for (int z = 0; z < d; ++z) catp[z] = sm_ai[c * 9 + aOff[l] + z];
      } else if (kind == 0) {     // aggregate: contract O(flat x*9+y) with cg
        const int l1 = colL1[col], l2 = colL2[col];
        const int d1 = DD[l1], d2 = DD[l2];
        const int x0 = aOff[l1], y0 = aOff[l2];
        const float* cgp = &sm_cg[colCg[col]];
        const float* Ofl = &arena[c * 81];
        for (int z = 0; z < d; ++z) {
          float sum = 0.f;
          for (int xi = 0; xi < d1; ++xi)
            for (int yi = 0; yi < d2; ++yi)
              sum += Ofl[(x0 + xi) * 9 + y0 + yi] * cgp[(xi * d2 + yi) * d + z];
          catp[z] = sum;
        }
      } else {                    // power: atom_i x atom_i
        const int l1 = colL1[col], l2 = colL2[col];
        const int d1 = DD[l1], d2 = DD[l2];
        const float* cgp = &sm_cg[colCg[col]];
        const float* a1p = &sm_ai[c * 9 + aOff[l1]];
        const float* a2p = &sm_ai[c * 9 + aOff[l2]];
        for (int z = 0; z < d; ++z) {
          float sum = 0.f;
          for (int xi = 0; xi < d1; ++xi)
            for (int yi = 0; yi < d2; ++yi)
              sum += a1p[xi] * a2p[yi] * cgp[(xi * d2 + yi) * d + z];
          catp[z] = sum;
        }
      }
    }
  }
  __syncthreads();

  // ---- channel mix (16-way k-split, shfl pair-combine -> 8 partials) ----
  {
    float accm[9];
    #pragma unroll
    for (int q = 0; q < 9; ++q) accm[q] = 0.f;
    const int co = c;
    #pragma unroll
    for (int k0 = 0; k0 < 224; k0 += 16) {
      const int k = k0 + s;
      accm[0] += arena[2592 + k] * p.w0[k * CC + co];
    }
    #pragma unroll
    for (int k0 = 0; k0 < 352; k0 += 16) {
      const int k = k0 + s;
      float wv = p.w1[k * CC + co];
      accm[1] += arena[2592 + 224 + k * 3 + 0] * wv;
      accm[2] += arena[2592 + 224 + k * 3 + 1] * wv;
      accm[3] += arena[2592 + 224 + k * 3 + 2] * wv;
    }
    #pragma unroll
    for (int k0 = 0; k0 < 416; k0 += 16) {
      const int k = k0 + s;
      float wv = p.w2[k * CC + co];
      #pragma unroll
      for (int z = 0; z < 5; ++z)
        accm[4 + z] += arena[2592 + 1280 + k * 5 + z] * wv;
    }
    #pragma unroll
    for (int q = 0; q < 9; ++q) accm[q] += __shfl_down(accm[q], 32);
    if ((s & 1) == 0) {
      #pragma unroll
      for (int q = 0; q < 9; ++q)
        arena[5952 + (s >> 1) * 288 + co * 9 + q] = accm[q];
    }
  }
  __syncthreads();

  // ---- final partial-sum + store ----
  if (tid < 288) {
    float v = 0.f;
    #pragma unroll
    for (int gg = 0; gg < 8; ++gg) v += arena[5952 + gg * 288 + tid];
    const int co = tid / 9, zz = tid - co * 9;
    const int nb = (b * NN + i) * CC;
    int oidx;
    if (zz == 0)     oidx = nb + co;                           // l=0
    else if (zz < 4) oidx = 32768  + (nb + co) * 3 + (zz - 1); // l=1
    else             oidx = 131072 + (nb + co) * 5 + (zz - 4); // l=2
    p.out[oidx] = v;
  }
}

extern "C" void kernel_launch(void* const* d_in, const int* in_sizes, int n_in,
                              void* d_out, int out_size, void* d_ws, size_t ws_size,
                              hipStream_t stream) {
  Params p;
  const bool interleaved = (in_sizes[1] == BB * NN * NN * CC);
  if (interleaved) {
    p.atom0 = (const float*)d_in[0]; p.edge0 = (const float*)d_in[1];
    p.atom1 = (const float*)d_in[2]; p.edge1 = (const float*)d_in[3];
    p.atom2 = (const float*)d_in[4]; p.edge2 = (const float*)d_in[5];
  } else {
    p.atom0 = (const float*)d_in[0]; p.atom1 = (const float*)d_in[1]; p.atom2 = (const float*)d_in[2];
    p.edge0 = (const float*)d_in[3]; p.edge1 = (const float*)d_in[4]; p.edge2 = (const float*)d_in[5];
  }
  p.mask = d_in[6];
  for (int t = 0; t < 14; ++t) p.cg[t] = (const float*)d_in[7 + t];
  p.w0 = (const float*)d_in[21];
  p.w1 = (const float*)d_in[22];
  p.w2 = (const float*)d_in[23];
  p.out = (float*)d_out;

  lgn_fused<<<dim3(BB * NN), dim3(512), 0, stream>>>(p);
}

// Round 11
// 68.151 us; speedup vs baseline: 1.8537x; 1.4598x over previous
//
#include <hip/hip_runtime.h>

#define BB 8
#define NN 128
#define CC 32

struct Params {
  const float* __restrict__ atom0; const float* __restrict__ atom1; const float* __restrict__ atom2;
  const float* __restrict__ edge0; const float* __restrict__ edge1; const float* __restrict__ edge2;
  const void*  mask;
  const float* __restrict__ cg[14];
  const float* __restrict__ w0; const float* __restrict__ w1; const float* __restrict__ w2;
  float* __restrict__ out;
};

// Block = (b,i), 512 threads.
// Loader role: thread = (kind, jl, c) — one 12-float LDS row per group (9 global
//   scalars -> 3x ds_write_b128). a-rows pre-multiplied by mask weight.
// Consumer role: thread = (c, jp, sx) — ds_read_b128 x2(+b32) per row.
// 2-deep pipeline: loads for group g+2 in flight while group g is consumed.
// Row layout: [c][12]: f0=l0-val, f1..3=l1, f4..8=l2 (9..11 pad). Buf = 6144 floats.
__global__ __launch_bounds__(512, 2) void lgn_fused(Params p) {
  const int tid = threadIdx.x;
  const int c   = tid & 31;
  const int s   = tid >> 5;      // 0..15
  const int sx  = s >> 3;        // consumer x-half
  const int jp  = s & 7;         // consumer j-slot
  const int kind = tid >> 8;     // loader: 0=e, 1=a (wave-uniform)
  const int jl   = (tid >> 5) & 7; // loader j-slot
  const int blk = blockIdx.x;
  const int b   = blk & 7;       // XCD-friendly
  const int i   = blk >> 3;

  // arena: dbuf 2x6144 | reuse: reduce slabs 2x2880 | O 0..2591, cat 2592..7551, mix 7552..9855
  __shared__ float arena[12288];
  __shared__ float sm_cg[540];
  __shared__ float sm_ai[288];
  __shared__ int   sm_list[128];
  __shared__ int   sm_nact, sm_mode;

  // ---- probe mask dtype ----
  if (tid == 0) sm_mode = 0;
  __syncthreads();
  if (tid < 64) {
    unsigned v = ((const unsigned*)p.mask)[tid];
    if (v == 0x3F800000u) atomicOr(&sm_mode, 2);   // float32
    else if (v > 1u)      atomicOr(&sm_mode, 1);   // packed bytes
  }
  // ---- stage cg + node-i atoms ----
  {
    constexpr int CGSZ[14] = {1,9,25, 9,9,27,45,45, 25,45,75,25,75,125};
    constexpr int CGOF[14] = {0,1,10, 35,44,53,80,125, 170,195,240,315,340,415};
    #pragma unroll
    for (int t = 0; t < 14; ++t)
      for (int idx = tid; idx < CGSZ[t]; idx += 512)
        sm_cg[CGOF[t] + idx] = p.cg[t][idx];
    const int nodeBase = (b * NN + i) * CC;
    for (int s2 = tid; s2 < 288; s2 += 512) {
      int cc = s2 / 9, comp = s2 - cc * 9;
      float v;
      if (comp == 0)      v = p.atom0[nodeBase + cc];
      else if (comp < 4)  v = p.atom1[(nodeBase + cc) * 3 + comp - 1];
      else                v = p.atom2[(nodeBase + cc) * 5 + comp - 4];
      sm_ai[s2] = v;
    }
  }
  __syncthreads();
  const int mode = (sm_mode & 2) ? 2 : sm_mode;

  // ---- ballot compaction of 128-j mask row (wave 0) ----
  if (tid < 64) {
    const int row = (b * NN + i) * NN;
    bool mv0, mv1;
    if (mode == 0) {
      mv0 = ((const int*)p.mask)[row + tid] != 0;
      mv1 = ((const int*)p.mask)[row + tid + 64] != 0;
    } else if (mode == 2) {
      mv0 = ((const float*)p.mask)[row + tid] != 0.f;
      mv1 = ((const float*)p.mask)[row + tid + 64] != 0.f;
    } else {
      mv0 = ((const unsigned char*)p.mask)[row + tid] != 0;
      mv1 = ((const unsigned char*)p.mask)[row + tid + 64] != 0;
    }
    unsigned long long b0 = __ballot(mv0);
    unsigned long long b1 = __ballot(mv1);
    int n0 = (int)__popcll(b0);
    unsigned long long lt = (1ull << tid) - 1ull;
    if (mv0) sm_list[__popcll(b0 & lt)] = tid;
    if (mv1) sm_list[n0 + __popcll(b1 & lt)] = tid + 64;
    if (tid == 0) sm_nact = n0 + (int)__popcll(b1);
  }
  __syncthreads();
  const int nact = sm_nact;
  const int nt   = (nact + 7) >> 3;
  if (tid < 64) {
    const int j0 = (nact > 0) ? sm_list[0] : 0;
    if (tid      >= nact) sm_list[tid]      = j0;
    if (tid + 64 >= nact) sm_list[tid + 64] = j0;
  }
  __syncthreads();

  // ---- loader bases (kind is wave-uniform) ----
  const float* P0; const float* P1; const float* P2;
  long base0, base1, base2;
  if (kind == 0) {
    P0 = p.edge0; P1 = p.edge1; P2 = p.edge2;
    base0 = (long)(b * NN + i) * NN * CC     + c;
    base1 = (long)(b * NN + i) * NN * CC * 3 + c * 3;
    base2 = (long)(b * NN + i) * NN * CC * 5 + c * 5;
  } else {
    P0 = p.atom0; P1 = p.atom1; P2 = p.atom2;
    base0 = (long)b * NN * CC     + c;
    base1 = (long)b * NN * CC * 3 + c * 3;
    base2 = (long)b * NN * CC * 5 + c * 5;
  }
  const int rowoff = kind * 3072 + (jl * 32 + c) * 12;

  float acc[5][9];
  #pragma unroll
  for (int k = 0; k < 5; ++k)
    #pragma unroll
    for (int y = 0; y < 9; ++y) acc[k][y] = 0.f;

#define LOADROW(V, G) do {                                                  \
    const int idx_ = (G) * 8 + jl;                                          \
    const int j_   = sm_list[idx_];                                         \
    V[0] = P0[base0 + (long)j_ * 32];                                       \
    V[1] = P1[base1 + (long)j_ * 96];                                       \
    V[2] = P1[base1 + (long)j_ * 96 + 1];                                   \
    V[3] = P1[base1 + (long)j_ * 96 + 2];                                   \
    V[4] = P2[base2 + (long)j_ * 160];                                      \
    V[5] = P2[base2 + (long)j_ * 160 + 1];                                  \
    V[6] = P2[base2 + (long)j_ * 160 + 2];                                  \
    V[7] = P2[base2 + (long)j_ * 160 + 3];                                  \
    V[8] = P2[base2 + (long)j_ * 160 + 4];                                  \
    if (kind) {                                                             \
      const float wt_ = (idx_ < nact) ? 1.f : 0.f;                          \
      _Pragma("unroll")                                                     \
      for (int q = 0; q < 9; ++q) V[q] *= wt_;                              \
    }                                                                       \
  } while (0)

#define WRITEROW(V, G) do {                                                 \
    float* dp_ = arena + ((G) & 1) * 6144 + rowoff;                         \
    *(float4*)(dp_)     = make_float4(V[0], V[1], V[2], V[3]);              \
    *(float4*)(dp_ + 4) = make_float4(V[4], V[5], V[6], V[7]);              \
    dp_[8] = V[8];                                                          \
  } while (0)

#define CONSUME(G) do {                                                     \
    const float* bp_ = arena + ((G) & 1) * 6144;                            \
    const float* er_ = bp_ + (jp * 32 + c) * 12;                            \
    const float4 ea_ = *(const float4*)(er_);                               \
    const float4 eb_ = *(const float4*)(er_ + 4);                           \
    const float  e8_ = er_[8];                                              \
    const float e_[9] = {ea_.x, ea_.y, ea_.z, ea_.w,                        \
                         eb_.x, eb_.y, eb_.z, eb_.w, e8_};                  \
    const float* ar_ = bp_ + 3072 + (jp * 32 + c) * 12;                     \
    if (sx == 0) {                                                          \
      const float4 aa_ = *(const float4*)(ar_);                             \
      const float a_[4] = {aa_.x, aa_.y, aa_.z, aa_.w};                     \
      _Pragma("unroll")                                                     \
      for (int k = 0; k < 4; ++k)                                           \
        _Pragma("unroll")                                                   \
        for (int y = 0; y < 9; ++y) acc[k][y] += a_[k] * e_[y];             \
    } else {                                                                \
      const float4 ab_ = *(const float4*)(ar_ + 4);                         \
      const float a_[5] = {ab_.x, ab_.y, ab_.z, ab_.w, ar_[8]};             \
      _Pragma("unroll")                                                     \
      for (int k = 0; k < 5; ++k)                                           \
        _Pragma("unroll")                                                   \
        for (int y = 0; y < 9; ++y) acc[k][y] += a_[k] * e_[y];             \
    }                                                                       \
  } while (0)

  if (nt > 0) {
    float vA[9], vB[9];
    LOADROW(vA, 0);
    WRITEROW(vA, 0);
    LOADROW(vB, 1);
    __syncthreads();
    for (int g = 0; g < nt; g += 2) {
      // even iter: vB holds g+1; buf[g&1] holds g
      if (g + 2 < 16) LOADROW(vA, g + 2);
      CONSUME(g);
      if (g + 1 < 16) WRITEROW(vB, g + 1);
      __syncthreads();
      if (g + 1 >= nt) break;
      // odd iter: vA holds g+2; buf[(g+1)&1] holds g+1
      if (g + 3 < 16) LOADROW(vB, g + 3);
      CONSUME(g + 1);
      if (g + 2 < 16) WRITEROW(vA, g + 2);
      __syncthreads();
    }
  }
#undef LOADROW
#undef WRITEROW
#undef CONSUME

  // ---- tree reduce 8 jp-slots (2 slabs of 45x64) ----
  const int sc = sx * 32 + c;
  if (jp >= 6) {
    float* sp = &arena[(jp - 6) * 2880 + sc];
    #pragma unroll
    for (int k = 0; k < 5; ++k)
      #pragma unroll
      for (int y = 0; y < 9; ++y) sp[(k * 9 + y) * 64] = acc[k][y];
  }
  __syncthreads();
  if (jp == 4 || jp == 5) {
    const float* sp = &arena[(jp - 4) * 2880 + sc];
    #pragma unroll
    for (int k = 0; k < 5; ++k)
      #pragma unroll
      for (int y = 0; y < 9; ++y) acc[k][y] += sp[(k * 9 + y) * 64];
  }
  __syncthreads();
  if (jp == 4 || jp == 5) {
    float* sp = &arena[(jp - 4) * 2880 + sc];
    #pragma unroll
    for (int k = 0; k < 5; ++k)
      #pragma unroll
      for (int y = 0; y < 9; ++y) sp[(k * 9 + y) * 64] = acc[k][y];
  }
  __syncthreads();
  if (jp <= 1) {
    const float* sp = &arena[jp * 2880 + sc];
    #pragma unroll
    for (int k = 0; k < 5; ++k)
      #pragma unroll
      for (int y = 0; y < 9; ++y) acc[k][y] += sp[(k * 9 + y) * 64];
  }
  __syncthreads();
  if (jp == 2 || jp == 3) {
    float* sp = &arena[(jp - 2) * 2880 + sc];
    #pragma unroll
    for (int k = 0; k < 5; ++k)
      #pragma unroll
      for (int y = 0; y < 9; ++y) sp[(k * 9 + y) * 64] = acc[k][y];
  }
  __syncthreads();
  if (jp <= 1) {
    const float* sp = &arena[jp * 2880 + sc];
    #pragma unroll
    for (int k = 0; k < 5; ++k)
      #pragma unroll
      for (int y = 0; y < 9; ++y) acc[k][y] += sp[(k * 9 + y) * 64];
  }
  #pragma unroll
  for (int k = 0; k < 5; ++k)
    #pragma unroll
    for (int y = 0; y < 9; ++y) acc[k][y] += __shfl_down(acc[k][y], 32);
  __syncthreads();   // slab reads done before O overwrites

  // ---- write final O flat [c][x*9+y] at arena[0..2591] ----
  if (s == 0) {
    #pragma unroll
    for (int k = 0; k < 4; ++k)
      #pragma unroll
      for (int y = 0; y < 9; ++y) arena[c * 81 + k * 9 + y] = acc[k][y];
  } else if (s == 8) {
    #pragma unroll
    for (int k = 0; k < 5; ++k)
      #pragma unroll
      for (int y = 0; y < 9; ++y) arena[c * 81 + (4 + k) * 9 + y] = acc[k][y];
  }
  __syncthreads();

  // ---- build cat: l0 [k] @2592, l1 [k][4] @2816, l2 [k][8] @4224 ----
  {
    constexpr int colL[31]   = {0,0,0,0,0,0,0, 1,1,1,1,1,1,1,1,1,1,1, 2,2,2,2,2,2,2,2,2,2,2,2,2};
    constexpr int colKind[31]= {0,0,0,1,2,2,2, 0,0,0,0,0,1,2,2,2,2,2, 0,0,0,0,0,0,1,2,2,2,2,2,2};
    constexpr int colL1[31]  = {0,1,2,0,0,1,2, 0,1,1,1,2,0,0,1,1,1,2, 0,1,1,2,2,2,0,0,1,1,2,2,2};
    constexpr int colL2[31]  = {0,1,2,0,0,1,2, 1,0,1,2,1,0,1,0,1,2,1, 2,1,2,0,1,2,0,2,1,2,0,1,2};
    constexpr int colCg[31]  = {0,1,10,0,0,1,10, 35,44,53,80,125,0,35,44,53,80,125,
                                170,195,240,315,340,415,0,170,195,240,315,340,415};
    constexpr int colP[31]   = {0,1,2,3,4,5,6, 0,1,2,3,4,5,6,7,8,9,10, 0,1,2,3,4,5,6,7,8,9,10,11,12};
    constexpr int DD[3]      = {1,3,5};
    constexpr int catBase[3] = {2592, 2816, 4224};
    constexpr int catStr[3]  = {1, 4, 8};
    constexpr int aOff[3]    = {0,1,4};

    for (int col = s; col < 31; col += 16) {
      const int l = colL[col];
      const int d = DD[l];
      const int knd = colKind[col];
      float* catp = &arena[catBase[l] + (colP[col] * CC + c) * catStr[l]];
      if (knd == 1) {             // identity
        for (int z = 0; z < d; ++z) catp[z] = sm_ai[c * 9 + aOff[l] + z];
      } else if (knd == 0) {      // aggregate: contract O(flat x*9+y) with cg
        const int l1 = colL1[col], l2 = colL2[col];
        const int d1 = DD[l1], d2 = DD[l2];
        const int x0 = aOff[l1], y0 = aOff[l2];
        const float* cgp = &sm_cg[colCg[col]];
        const float* Ofl = &arena[c * 81];
        for (int z = 0; z < d; ++z) {
          float sum = 0.f;
          for (int xi = 0; xi < d1; ++xi)
            for (int yi = 0; yi < d2; ++yi)
              sum += Ofl[(x0 + xi) * 9 + y0 + yi] * cgp[(xi * d2 + yi) * d + z];
          catp[z] = sum;
        }
      } else {                    // power: atom_i x atom_i
        const int l1 = colL1[col], l2 = colL2[col];
        const int d1 = DD[l1], d2 = DD[l2];
        const float* cgp = &sm_cg[colCg[col]];
        const float* a1p = &sm_ai[c * 9 + aOff[l1]];
        const float* a2p = &sm_ai[c * 9 + aOff[l2]];
        for (int z = 0; z < d; ++z) {
          float sum = 0.f;
          for (int xi = 0; xi < d1; ++xi)
            for (int yi = 0; yi < d2; ++yi)
              sum += a1p[xi] * a2p[yi] * cgp[(xi * d2 + yi) * d + z];
          catp[z] = sum;
        }
      }
    }
  }
  __syncthreads();

  // ---- channel mix (16-way k-split, wide LDS reads, shfl pair-combine) ----
  {
    float accm[9];
    #pragma unroll
    for (int q = 0; q < 9; ++q) accm[q] = 0.f;
    const int co = c;
    #pragma unroll
    for (int k0 = 0; k0 < 224; k0 += 16) {
      const int k = k0 + s;
      accm[0] += arena[2592 + k] * p.w0[k * CC + co];
    }
    #pragma unroll
    for (int k0 = 0; k0 < 352; k0 += 16) {
      const int k = k0 + s;
      const float4 v = *(const float4*)&arena[2816 + k * 4];
      const float wv = p.w1[k * CC + co];
      accm[1] += v.x * wv;
      accm[2] += v.y * wv;
      accm[3] += v.z * wv;
    }
    #pragma unroll
    for (int k0 = 0; k0 < 416; k0 += 16) {
      const int k = k0 + s;
      const float4 v = *(const float4*)&arena[4224 + k * 8];
      const float v4 = arena[4224 + k * 8 + 4];
      const float wv = p.w2[k * CC + co];
      accm[4] += v.x * wv;
      accm[5] += v.y * wv;
      accm[6] += v.z * wv;
      accm[7] += v.w * wv;
      accm[8] += v4  * wv;
    }
    #pragma unroll
    for (int q = 0; q < 9; ++q) accm[q] += __shfl_down(accm[q], 32);
    if ((s & 1) == 0) {
      #pragma unroll
      for (int q = 0; q < 9; ++q)
        arena[7552 + (s >> 1) * 288 + co * 9 + q] = accm[q];
    }
  }
  __syncthreads();

  // ---- final partial-sum + store ----
  if (tid < 288) {
    float v = 0.f;
    #pragma unroll
    for (int gg = 0; gg < 8; ++gg) v += arena[7552 + gg * 288 + tid];
    const int co = tid / 9, zz = tid - co * 9;
    const int nb = (b * NN + i) * CC;
    int oidx;
    if (zz == 0)     oidx = nb + co;                           // l=0
    else if (zz < 4) oidx = 32768  + (nb + co) * 3 + (zz - 1); // l=1
    else             oidx = 131072 + (nb + co) * 5 + (zz - 4); // l=2
    p.out[oidx] = v;
  }
}

extern "C" void kernel_launch(void* const* d_in, const int* in_sizes, int n_in,
                              void* d_out, int out_size, void* d_ws, size_t ws_size,
                              hipStream_t stream) {
  Params p;
  const bool interleaved = (in_sizes[1] == BB * NN * NN * CC);
  if (interleaved) {
    p.atom0 = (const float*)d_in[0]; p.edge0 = (const float*)d_in[1];
    p.atom1 = (const float*)d_in[2]; p.edge1 = (const float*)d_in[3];
    p.atom2 = (const float*)d_in[4]; p.edge2 = (const float*)d_in[5];
  } else {
    p.atom0 = (const float*)d_in[0]; p.atom1 = (const float*)d_in[1]; p.atom2 = (const float*)d_in[2];
    p.edge0 = (const float*)d_in[3]; p.edge1 = (const float*)d_in[4]; p.edge2 = (const float*)d_in[5];
  }
  p.mask = d_in[6];
  for (int t = 0; t < 14; ++t) p.cg[t] = (const float*)d_in[7 + t];
  p.w0 = (const float*)d_in[21];
  p.w1 = (const float*)d_in[22];
  p.w2 = (const float*)d_in[23];
  p.out = (float*)d_out;

  lgn_fused<<<dim3(BB * NN), dim3(512), 0, stream>>>(p);
}

// Round 13
// 60.656 us; speedup vs baseline: 2.0827x; 1.1236x over previous
//
#include <hip/hip_runtime.h>

#define BB 8
#define NN 128
#define CC 32

typedef short bf16x8 __attribute__((ext_vector_type(8)));
typedef float f32x4  __attribute__((ext_vector_type(4)));

static __device__ __forceinline__ unsigned f2bf(float f) {
  union { float f; unsigned u; } v; v.f = f;
  unsigned r = v.u + 0x7FFFu + ((v.u >> 16) & 1u);   // RNE
  return r >> 16;
}

struct Params {
  const float* __restrict__ atom0; const float* __restrict__ atom1; const float* __restrict__ atom2;
  const float* __restrict__ edge0; const float* __restrict__ edge1; const float* __restrict__ edge2;
  const void*  mask;
  const float* __restrict__ cg[14];
  const float* __restrict__ w0; const float* __restrict__ w1; const float* __restrict__ w2;
  float* __restrict__ out;
};

// Block = (b,i), 512 threads = 8 waves. Aggregation via MFMA (16x16x32 bf16):
// per channel c, O[x][y] = sum_j a[j][c][x]*wt[j] * e[j][c][y]
// LDS A-tile per channel: [x:16][k:32] bf16 (k contiguous) @ c*1024B; B same @ +32KB.
// Only rows x<=8 written (rows 9..15 feed discarded D rows/cols only).
// XOR swizzle byte ^= ((x^c)&7)<<4 : spreads write banks (lanes vary c),
// relocates whole 16B blocks so b128 fragment reads stay contiguous.
// A-frag: lane l = row (l&15), k = (l>>4)*8 .. +7 (standard layout).
// C/D (m89-verified): col = lane&15, row = (lane>>4)*4 + reg.
__global__ __launch_bounds__(512, 2) void lgn_fused(Params p) {
  const int tid  = threadIdx.x;
  const int c    = tid & 31;
  const int s    = tid >> 5;     // 0..15
  const int lane = tid & 63;
  const int wv   = tid >> 6;     // wave 0..7
  const int blk  = blockIdx.x;
  const int b    = blk & 7;      // XCD-friendly
  const int i    = blk >> 3;

  // arena (64KB): main loop = A/B bf16 tiles; epilogue reuse as f32:
  //   O flat 0..2591 | cat (l0@2592, l1[k][4]@2816, l2[k][8]@4224) | mix 7552..9855
  __shared__ float arena[16384];
  __shared__ float sm_cg[540];
  __shared__ float sm_ai[288];
  __shared__ int   sm_list[128];
  __shared__ int   sm_nact, sm_mode;
  char* smb = (char*)arena;

  // ---- probe mask dtype ----
  if (tid == 0) sm_mode = 0;
  __syncthreads();
  if (tid < 64) {
    unsigned v = ((const unsigned*)p.mask)[tid];
    if (v == 0x3F800000u) atomicOr(&sm_mode, 2);   // float32
    else if (v > 1u)      atomicOr(&sm_mode, 1);   // packed bytes
  }
  // ---- stage cg + node-i atoms ----
  {
    constexpr int CGSZ[14] = {1,9,25, 9,9,27,45,45, 25,45,75,25,75,125};
    constexpr int CGOF[14] = {0,1,10, 35,44,53,80,125, 170,195,240,315,340,415};
    #pragma unroll
    for (int t = 0; t < 14; ++t)
      for (int idx = tid; idx < CGSZ[t]; idx += 512)
        sm_cg[CGOF[t] + idx] = p.cg[t][idx];
    const int nodeBase = (b * NN + i) * CC;
    for (int s2 = tid; s2 < 288; s2 += 512) {
      int cc = s2 / 9, comp = s2 - cc * 9;
      float v;
      if (comp == 0)      v = p.atom0[nodeBase + cc];
      else if (comp < 4)  v = p.atom1[(nodeBase + cc) * 3 + comp - 1];
      else                v = p.atom2[(nodeBase + cc) * 5 + comp - 4];
      sm_ai[s2] = v;
    }
  }
  __syncthreads();
  const int mode = (sm_mode & 2) ? 2 : sm_mode;

  // ---- ballot compaction of 128-j mask row (wave 0) ----
  if (tid < 64) {
    const int row = (b * NN + i) * NN;
    bool mv0, mv1;
    if (mode == 0) {
      mv0 = ((const int*)p.mask)[row + tid] != 0;
      mv1 = ((const int*)p.mask)[row + tid + 64] != 0;
    } else if (mode == 2) {
      mv0 = ((const float*)p.mask)[row + tid] != 0.f;
      mv1 = ((const float*)p.mask)[row + tid + 64] != 0.f;
    } else {
      mv0 = ((const unsigned char*)p.mask)[row + tid] != 0;
      mv1 = ((const unsigned char*)p.mask)[row + tid + 64] != 0;
    }
    unsigned long long b0 = __ballot(mv0);
    unsigned long long b1 = __ballot(mv1);
    int n0 = (int)__popcll(b0);
    unsigned long long lt = (1ull << tid) - 1ull;
    if (mv0) sm_list[__popcll(b0 & lt)] = tid;
    if (mv1) sm_list[n0 + __popcll(b1 & lt)] = tid + 64;
    if (tid == 0) sm_nact = n0 + (int)__popcll(b1);
  }
  __syncthreads();
  const int nact = sm_nact;
  const int nch  = (nact + 31) >> 5;   // chunks of 32 j
  if (tid < 64) {
    const int j0 = (nact > 0) ? sm_list[0] : 0;
    if (tid      >= nact) sm_list[tid]      = j0;
    if (tid + 64 >= nact) sm_list[tid + 64] = j0;
  }
  __syncthreads();

  // ---- main loop: stage chunk (bf16 [x][k] tiles) -> MFMA consume ----
  const long en0 = (long)(b * NN + i) * NN * CC;   // e0 element base
  const long an0 = (long)b * NN * CC;              // a0 element base

  f32x4 acc[4];
  #pragma unroll
  for (int q = 0; q < 4; ++q) acc[q] = (f32x4){0.f, 0.f, 0.f, 0.f};

  const int cbase = wv * 4;
  const int xr    = lane & 15;          // fragment row (A) / col (B)
  const int g16   = (lane >> 4) * 16;   // k-group byte offset (8 bf16)

  for (int ch = 0; ch < nch; ++ch) {
    // ---------- stage: 2 slots per thread; 18 swizzled b16 writes each ----------
    #pragma unroll
    for (int half = 0; half < 2; ++half) {
      const int sl = ch * 32 + s + half * 16;
      const int jg = sm_list[sl];
      const float wt = (sl < nact) ? 1.f : 0.f;
      float A[9], E[9];
      {
        const long a1b = an0 * 3 + (long)jg * 96 + c * 3;
        const long a2b = an0 * 5 + (long)jg * 160 + c * 5;
        A[0] = p.atom0[an0 + (long)jg * 32 + c];
        A[1] = p.atom1[a1b + 0]; A[2] = p.atom1[a1b + 1]; A[3] = p.atom1[a1b + 2];
        A[4] = p.atom2[a2b + 0]; A[5] = p.atom2[a2b + 1]; A[6] = p.atom2[a2b + 2];
        A[7] = p.atom2[a2b + 3]; A[8] = p.atom2[a2b + 4];
        const long e1b = en0 * 3 + (long)jg * 96 + c * 3;
        const long e2b = en0 * 5 + (long)jg * 160 + c * 5;
        E[0] = p.edge0[en0 + (long)jg * 32 + c];
        E[1] = p.edge1[e1b + 0]; E[2] = p.edge1[e1b + 1]; E[3] = p.edge1[e1b + 2];
        E[4] = p.edge2[e2b + 0]; E[5] = p.edge2[e2b + 1]; E[6] = p.edge2[e2b + 2];
        E[7] = p.edge2[e2b + 3]; E[8] = p.edge2[e2b + 4];
      }
      const int kk = s + half * 16;        // k slot 0..31
      #pragma unroll
      for (int x = 0; x < 9; ++x) {
        const unsigned ba = ((unsigned)(c * 1024 + x * 64 + kk * 2))
                          ^ ((unsigned)(((x ^ c) & 7) << 4));
        *(unsigned short*)(smb + ba)         = (unsigned short)f2bf(A[x] * wt);
        *(unsigned short*)(smb + 32768 + ba) = (unsigned short)f2bf(E[x]);
      }
    }
    __syncthreads();

    // ---------- consume: 4 channels x (2 b128 reads + 1 MFMA) ----------
    #pragma unroll
    for (int q = 0; q < 4; ++q) {
      const int cq = cbase + q;
      const unsigned ba = ((unsigned)(cq * 1024 + xr * 64 + g16))
                        ^ ((unsigned)(((xr ^ cq) & 7) << 4));
      const bf16x8 fa = *(const bf16x8*)(smb + ba);
      const bf16x8 fb = *(const bf16x8*)(smb + 32768 + ba);
      acc[q] = __builtin_amdgcn_mfma_f32_16x16x32_bf16(fa, fb, acc[q], 0, 0, 0);
    }
    __syncthreads();
  }

  // ---- scatter O frags to arena[c*81 + x*9 + y] (f32) ----
  {
    const int ycol = lane & 15;                    // D col = y
    const int xb   = (lane >> 4) * 4;              // D row base = x
    if (ycol < 9) {
      #pragma unroll
      for (int q = 0; q < 4; ++q) {
        #pragma unroll
        for (int r = 0; r < 4; ++r) {
          const int x = xb + r;
          if (x < 9) arena[(cbase + q) * 81 + x * 9 + ycol] = acc[q][r];
        }
      }
    }
  }
  __syncthreads();

  // ---- build cat: l0 [k] @2592, l1 [k][4] @2816, l2 [k][8] @4224 ----
  {
    constexpr int colL[31]   = {0,0,0,0,0,0,0, 1,1,1,1,1,1,1,1,1,1,1, 2,2,2,2,2,2,2,2,2,2,2,2,2};
    constexpr int colKind[31]= {0,0,0,1,2,2,2, 0,0,0,0,0,1,2,2,2,2,2, 0,0,0,0,0,0,1,2,2,2,2,2,2};
    constexpr int colL1[31]  = {0,1,2,0,0,1,2, 0,1,1,1,2,0,0,1,1,1,2, 0,1,1,2,2,2,0,0,1,1,2,2,2};
    constexpr int colL2[31]  = {0,1,2,0,0,1,2, 1,0,1,2,1,0,1,0,1,2,1, 2,1,2,0,1,2,0,2,1,2,0,1,2};
    constexpr int colCg[31]  = {0,1,10,0,0,1,10, 35,44,53,80,125,0,35,44,53,80,125,
                                170,195,240,315,340,415,0,170,195,240,315,340,415};
    constexpr int colP[31]   = {0,1,2,3,4,5,6, 0,1,2,3,4,5,6,7,8,9,10, 0,1,2,3,4,5,6,7,8,9,10,11,12};
    constexpr int DD[3]      = {1,3,5};
    constexpr int catBase[3] = {2592, 2816, 4224};
    constexpr int catStr[3]  = {1, 4, 8};
    constexpr int aOff[3]    = {0,1,4};

    for (int col = s; col < 31; col += 16) {
      const int l = colL[col];
      const int d = DD[l];
      const int knd = colKind[col];
      float* catp = &arena[catBase[l] + (colP[col] * CC + c) * catStr[l]];
      if (knd == 1) {             // identity
        for (int z = 0; z < d; ++z) catp[z] = sm_ai[c * 9 + aOff[l] + z];
      } else if (knd == 0) {      // aggregate: contract O(flat x*9+y) with cg
        const int l1 = colL1[col], l2 = colL2[col];
        const int d1 = DD[l1], d2 = DD[l2];
        const int x0 = aOff[l1], y0 = aOff[l2];
        const float* cgp = &sm_cg[colCg[col]];
        const float* Ofl = &arena[c * 81];
        for (int z = 0; z < d; ++z) {
          float sum = 0.f;
          for (int xi = 0; xi < d1; ++xi)
            for (int yi = 0; yi < d2; ++yi)
              sum += Ofl[(x0 + xi) * 9 + y0 + yi] * cgp[(xi * d2 + yi) * d + z];
          catp[z] = sum;
        }
      } else {                    // power: atom_i x atom_i
        const int l1 = colL1[col], l2 = colL2[col];
        const int d1 = DD[l1], d2 = DD[l2];
        const float* cgp = &sm_cg[colCg[col]];
        const float* a1p = &sm_ai[c * 9 + aOff[l1]];
        const float* a2p = &sm_ai[c * 9 + aOff[l2]];
        for (int z = 0; z < d; ++z) {
          float sum = 0.f;
          for (int xi = 0; xi < d1; ++xi)
            for (int yi = 0; yi < d2; ++yi)
              sum += a1p[xi] * a2p[yi] * cgp[(xi * d2 + yi) * d + z];
          catp[z] = sum;
        }
      }
    }
  }
  __syncthreads();

  // ---- channel mix (16-way k-split, wide LDS reads, shfl pair-combine) ----
  {
    float accm[9];
    #pragma unroll
    for (int q = 0; q < 9; ++q) accm[q] = 0.f;
    const int co = c;
    #pragma unroll
    for (int k0 = 0; k0 < 224; k0 += 16) {
      const int k = k0 + s;
      accm[0] += arena[2592 + k] * p.w0[k * CC + co];
    }
    #pragma unroll
    for (int k0 = 0; k0 < 352; k0 += 16) {
      const int k = k0 + s;
      const float4 v = *(const float4*)&arena[2816 + k * 4];
      const float wv2 = p.w1[k * CC + co];
      accm[1] += v.x * wv2;
      accm[2] += v.y * wv2;
      accm[3] += v.z * wv2;
    }
    #pragma unroll
    for (int k0 = 0; k0 < 416; k0 += 16) {
      const int k = k0 + s;
      const float4 v = *(const float4*)&arena[4224 + k * 8];
      const float v4 = arena[4224 + k * 8 + 4];
      const float wv2 = p.w2[k * CC + co];
      accm[4] += v.x * wv2;
      accm[5] += v.y * wv2;
      accm[6] += v.z * wv2;
      accm[7] += v.w * wv2;
      accm[8] += v4  * wv2;
    }
    #pragma unroll
    for (int q = 0; q < 9; ++q) accm[q] += __shfl_down(accm[q], 32);
    if ((s & 1) == 0) {
      #pragma unroll
      for (int q = 0; q < 9; ++q)
        arena[7552 + (s >> 1) * 288 + co * 9 + q] = accm[q];
    }
  }
  __syncthreads();

  // ---- final partial-sum + store ----
  if (tid < 288) {
    float v = 0.f;
    #pragma unroll
    for (int gg = 0; gg < 8; ++gg) v += arena[7552 + gg * 288 + tid];
    const int co = tid / 9, zz = tid - co * 9;
    const int nb = (b * NN + i) * CC;
    int oidx;
    if (zz == 0)     oidx = nb + co;                           // l=0
    else if (zz < 4) oidx = 32768  + (nb + co) * 3 + (zz - 1); // l=1
    else             oidx = 131072 + (nb + co) * 5 + (zz - 4); // l=2
    p.out[oidx] = v;
  }
}

extern "C" void kernel_launch(void* const* d_in, const int* in_sizes, int n_in,
                              void* d_out, int out_size, void* d_ws, size_t ws_size,
                              hipStream_t stream) {
  Params p;
  const bool interleaved = (in_sizes[1] == BB * NN * NN * CC);
  if (interleaved) {
    p.atom0 = (const float*)d_in[0]; p.edge0 = (const float*)d_in[1];
    p.atom1 = (const float*)d_in[2]; p.edge1 = (const float*)d_in[3];
    p.atom2 = (const float*)d_in[4]; p.edge2 = (const float*)d_in[5];
  } else {
    p.atom0 = (const float*)d_in[0]; p.atom1 = (const float*)d_in[1]; p.atom2 = (const float*)d_in[2];
    p.edge0 = (const float*)d_in[3]; p.edge1 = (const float*)d_in[4]; p.edge2 = (const float*)d_in[5];
  }
  p.mask = d_in[6];
  for (int t = 0; t < 14; ++t) p.cg[t] = (const float*)d_in[7 + t];
  p.w0 = (const float*)d_in[21];
  p.w1 = (const float*)d_in[22];
  p.w2 = (const float*)d_in[23];
  p.out = (float*)d_out;

  lgn_fused<<<dim3(BB * NN), dim3(512), 0, stream>>>(p);
}